// Round 7
// baseline (230.602 us; speedup 1.0000x reference)
//
#include <hip/hip_runtime.h>
#include <hip/hip_bf16.h>
#include <stdint.h>

// B=2, L=2048, E=1024, H=16, Dh=64. f32 in/out; bf16 MFMA compute.
// Layouts (workspace, produced by proj_gemm):
//   QH [b,h,q,64d]               : q-row = 128B contiguous
//   KH [b,h,kt][dh2][64k][32d]   : 8KB contiguous per (b,h,kt) tile
//   VTB[b,h,kt][kk2][64d][32k]   : 8KB contiguous per tile (V transposed)
#define B_    2
#define SEQ   2048
#define EMB   1024
#define LOG2E 1.4426950408889634f
#define BIG2F (1e10f * LOG2E)
#define C2    (0.125f * LOG2E)
#define PS    72    // P row stride (u16): 144B rows -> 16B-aligned, 4-way banks

typedef unsigned short u16;
typedef __attribute__((ext_vector_type(4)))  u16   u16x4;
typedef __attribute__((ext_vector_type(8)))  short bf8;   // MFMA A/B frag (16B)
typedef __attribute__((ext_vector_type(4)))  float f4;    // 16x16 C/D frag
typedef __attribute__((ext_vector_type(16))) float fx16;  // 32x32 C/D frag
typedef __attribute__((ext_vector_type(4)))  float fv4;

__device__ inline float bf2f(u16 u){ union{uint32_t i; float f;} v; v.i = ((uint32_t)u) << 16; return v.f; }
__device__ inline u16 f2bf(float f){ union{float f; uint32_t i;} v; v.f = f;
                                     uint32_t r = v.i + 0x7fffu + ((v.i >> 16) & 1u); return (u16)(r >> 16); }
__device__ inline float exp2_hw(float x){ float r; asm("v_exp_f32 %0, %1" : "=v"(r) : "v"(x)); return r; }

__device__ inline void gl_lds16(const void* g, void* l){
  __builtin_amdgcn_global_load_lds((const __attribute__((address_space(1))) uint32_t*)g,
                                   (__attribute__((address_space(3))) uint32_t*)l, 16, 0, 0);
}

// ---------------- f32 -> bf16 conversion (6 segments) + seg 6: pen = (1-vmask)*BIG2F (f32)
struct CvtArgs { const float* src[7]; u16* dst[7]; int n[7]; };

__global__ __launch_bounds__(256) void cvt_bf16(CvtArgs a)
{
  const int seg = blockIdx.y;
  const float* __restrict__ s = a.src[seg];
  const int n = a.n[seg];
  const int i = (blockIdx.x * 256 + threadIdx.x) * 8;
  if (i >= n) return;
  fv4 x0 = *(const fv4*)(s + i);
  fv4 x1 = *(const fv4*)(s + i + 4);
  if (seg == 6) {                       // pen precompute, f32 out
    float* pd = (float*)a.dst[6];
    fv4 p0, p1;
#pragma unroll
    for (int j = 0; j < 4; j++) { p0[j] = (1.0f - x0[j]) * BIG2F; p1[j] = (1.0f - x1[j]) * BIG2F; }
    *(fv4*)(pd + i) = p0;
    *(fv4*)(pd + i + 4) = p1;
    return;
  }
  u16* __restrict__ d = a.dst[seg];
  union { bf8 v; u16 u[8]; } o;
#pragma unroll
  for (int j = 0; j < 4; j++) { o.u[j] = f2bf(x0[j]); o.u[4 + j] = f2bf(x1[j]); }
  *(bf8*)(d + i) = o.v;
}

// ---------------- Projection GEMM (NT), BK=64, coalesced epilogues (unchanged from R6).
__global__ __launch_bounds__(256) void proj_gemm(
    const u16* __restrict__ Xq, const u16* __restrict__ Xk, const u16* __restrict__ Xv,
    const u16* __restrict__ Wq, const u16* __restrict__ Wk, const u16* __restrict__ Wv,
    u16* __restrict__ QH, u16* __restrict__ KH, u16* __restrict__ VTB)
{
  __shared__ u16 smem[18432];
  u16* lA = smem;                   // [kk2][128][32]
  u16* lB = smem + 8192;

  const int z = blockIdx.z;
  const u16* X = (z == 0) ? Xq : ((z == 1) ? Xk : Xv);
  const u16* W = (z == 0) ? Wq : ((z == 1) ? Wk : Wv);

  const int tid  = threadIdx.x;
  const int lane = tid & 63;
  const int w    = tid >> 6;
  const int wm   = w >> 1, wn = w & 1;
  const int m0   = blockIdx.x * 128;
  const int n0   = blockIdx.y * 128;
  const int col  = lane & 15, quad = lane >> 4;

  const f4 zero = {0.f, 0.f, 0.f, 0.f};
  f4 acc[4][4];
#pragma unroll
  for (int i = 0; i < 4; i++)
#pragma unroll
    for (int j = 0; j < 4; j++) acc[i][j] = zero;

  for (int k0 = 0; k0 < 1024; k0 += 64) {
    __syncthreads();
#pragma unroll
    for (int j = 0; j < 4; j++) {
      const int kk  = j >> 1;
      const int row = (j & 1) * 64 + w * 16 + (lane >> 2);
      const int cc  = (lane & 3) * 8;
      const size_t g = (size_t)row * 1024 + k0 + kk * 32 + cc;
      gl_lds16(X + (size_t)m0 * 1024 + g, &lA[(j * 256 + w * 64) * 8]);
      gl_lds16(W + (size_t)n0 * 1024 + g, &lB[(j * 256 + w * 64) * 8]);
    }
    __syncthreads();
#pragma unroll
    for (int kk = 0; kk < 2; kk++) {
      const int koff = kk * 4096 + quad * 8;
      bf8 a[4], b[4];
#pragma unroll
      for (int t = 0; t < 4; t++) a[t] = *(const bf8*)&lA[koff + (wm * 64 + t * 16 + col) * 32];
#pragma unroll
      for (int t = 0; t < 4; t++) b[t] = *(const bf8*)&lB[koff + (wn * 64 + t * 16 + col) * 32];
#pragma unroll
      for (int mt = 0; mt < 4; mt++)
#pragma unroll
        for (int nt = 0; nt < 4; nt++)
          acc[mt][nt] = __builtin_amdgcn_mfma_f32_16x16x32_bf16(a[mt], b[nt], acc[mt][nt], 0, 0, 0);
    }
  }

  __syncthreads();
  u16* ep = &smem[w * 4608];            // 64 x 72

  if (z == 2) {
#pragma unroll
    for (int mt = 0; mt < 4; mt++)
#pragma unroll
      for (int nt = 0; nt < 4; nt++) {
        u16x4 pk = { f2bf(acc[mt][nt][0]), f2bf(acc[mt][nt][1]),
                     f2bf(acc[mt][nt][2]), f2bf(acc[mt][nt][3]) };
        *(u16x4*)&ep[(nt * 16 + col) * 72 + mt * 16 + quad * 4] = pk;
      }
  } else {
#pragma unroll
    for (int mt = 0; mt < 4; mt++)
#pragma unroll
      for (int nt = 0; nt < 4; nt++)
#pragma unroll
        for (int r = 0; r < 4; r++)
          ep[(mt * 16 + quad * 4 + r) * 72 + nt * 16 + col] = f2bf(acc[mt][nt][r]);
  }

  const int bb = m0 >> 11;
  const int h  = (n0 >> 6) + wn;
  const int bh = bb * 16 + h;

  if (z == 0) {
    const int qbase = (m0 & 2047) + wm * 64;
    u16* dst = QH + ((size_t)bh * SEQ + qbase) * 64;
#pragma unroll
    for (int i = 0; i < 8; i++) {
      const int f  = i * 1024 + lane * 16;
      const int ml = i * 8 + (lane >> 3), nl = (lane & 7) * 8;
      *(bf8*)(dst + (f >> 1)) = *(const bf8*)&ep[ml * 72 + nl];
    }
  } else if (z == 1) {
    const int kt = (((m0 & 2047) >> 6) + wm);
    u16* dst = KH + (((size_t)bh * 32 + kt) << 12);
#pragma unroll
    for (int i = 0; i < 8; i++) {
      const int f   = i * 1024 + lane * 16;
      const int dh  = f >> 12;
      const int klc = (f >> 6) & 63;
      const int dlo = (lane & 3) * 8;
      *(bf8*)(dst + (f >> 1)) = *(const bf8*)&ep[klc * 72 + dh * 32 + dlo];
    }
  } else {
    const int kt = (((m0 & 2047) >> 6) + wm);
    u16* dst = VTB + (((size_t)bh * 32 + kt) << 12);
#pragma unroll
    for (int i = 0; i < 8; i++) {
      const int f   = i * 1024 + lane * 16;
      const int kk  = f >> 12;
      const int d   = (f >> 6) & 63;
      const int klo = (lane & 3) * 8;
      *(bf8*)(dst + (f >> 1)) = *(const bf8*)&ep[d * 72 + kk * 32 + klo];
    }
  }
}

// ---------------- masked V mean (dead-row fallback), vectorized.
// Block = (bh, half32): 4 waves x 8 d each; lane: d = base+(lane>>3), 4 keys at (lane&7)*4.
__global__ __launch_bounds__(256) void sumv(const u16* __restrict__ VTB,
                                            const float* __restrict__ vmask,
                                            float* __restrict__ fb)
{
  const int w = threadIdx.x >> 6, lane = threadIdx.x & 63;
  const int bh = blockIdx.x >> 1, half = blockIdx.x & 1;
  const int b = bh >> 4, h = bh & 15;
  const int d = half * 32 + w * 8 + (lane >> 3);
  const int k4 = (lane & 7) * 4;
  const u16* tb = VTB + ((size_t)bh << 17);
  const float* vm = vmask + b * SEQ;
  float s = 0.f, c = 0.f;
  for (int kt = 0; kt < 32; kt++)
#pragma unroll
    for (int kk = 0; kk < 2; kk++) {
      union { u16x4 v; u16 u[4]; } x;
      x.v = *(const u16x4*)(tb + (kt << 12) + kk * 2048 + d * 32 + k4);
      fv4 m = *(const fv4*)(vm + kt * 64 + kk * 32 + k4);
#pragma unroll
      for (int j = 0; j < 4; j++) { s += m[j] * bf2f(x.u[j]); c += m[j]; }
    }
#pragma unroll
  for (int o = 1; o < 8; o <<= 1) { s += __shfl_xor(s, o); c += __shfl_xor(c, o); }
  if ((lane & 7) == 0) fb[b * 1024 + h * 64 + d] = s / c;
}

// ---------------- Flash attention v4: 32x32x16 MFMA, 2-wave blocks, 64 q-rows/wave.
// S^T = K Q^T, O^T = V^T P^T. Wave-private P (no inner barrier for P), pen via global
// fv4 (VMEM pipe), per-wave causal skip/diag, dbuf K/V staging (1 barrier/tile),
// XCD-clustered bh, qb paired across dispatch rounds for per-CU load balance.
__global__ __launch_bounds__(128, 2) void attn(
    const u16* __restrict__ QH, const u16* __restrict__ KH, const u16* __restrict__ VTB,
    const float* __restrict__ penG, const float* __restrict__ qmask,
    const float* __restrict__ fb, float* __restrict__ OUT)
{
  __shared__ u16 sK[2][4096];        // [dh2][64key][32d] x2
  __shared__ u16 sV[2][4096];        // [kk2][64d][32k]   x2
  __shared__ u16 P[2][64 * PS];      // per-wave P^T: [q64][keypad]

  const int tid = threadIdx.x, lane = tid & 63, wq = tid >> 6;
  const int lm = lane & 31, hi = lane >> 5;
  const int i  = blockIdx.x;                 // 0..511
  const int lo = i & 255, rnd = i >> 8;
  const int xcd = lo & 7, g = lo >> 3;
  const int bh  = xcd + 8 * (g & 3);         // 4 bh per XCD -> ~2MB KV in 4MB L2
  const int f   = g >> 2;                    // 0..7
  const int qb  = rnd ? (15 - f) : f;        // paired big/small across dispatch rounds
  const int b = bh >> 4, h = bh & 15;
  const int q0 = qb * 128;
  const int t0 = 2 * qb, ntile = 32 - t0;

  const u16* kbase = KH  + ((size_t)bh << 17);
  const u16* vbase = VTB + ((size_t)bh << 17);
  const float* penB = penG + b * SEQ;
  u16* Pw = P[wq];

  // Q B-frags (n = q = qt*32+lm, k = kc*16 + hi*8 + j), held in regs
  bf8 bQ[2][4];
#pragma unroll
  for (int qt = 0; qt < 2; qt++)
#pragma unroll
    for (int kc = 0; kc < 4; kc++)
      bQ[qt][kc] = *(const bf8*)&QH[((size_t)bh * SEQ + q0 + wq * 64 + qt * 32 + lm) * 64 + kc * 16 + hi * 8];

  fx16 accO[2][2];
#pragma unroll
  for (int a = 0; a < 2; a++)
#pragma unroll
    for (int c = 0; c < 2; c++)
#pragma unroll
      for (int r = 0; r < 16; r++) accO[a][c][r] = 0.f;
  float l_part[2] = {0.f, 0.f};

  // prologue: stage tile t0 -> buf 0 (each wave stages its 4KB halves of K and V)
  {
    const size_t so = ((size_t)t0 << 12) + wq * 2048 + lane * 8;
#pragma unroll
    for (int s2 = 0; s2 < 4; s2++) {
      gl_lds16(kbase + so + s2 * 512, &sK[0][wq * 2048 + s2 * 512]);
      gl_lds16(vbase + so + s2 * 512, &sV[0][wq * 2048 + s2 * 512]);
    }
  }

  for (int it = 0; it < ntile; it++) {
    __syncthreads();                          // buf[it&1] staged (vmcnt drained)
    if (it + 1 < ntile) {                     // prefetch next tile
      const int nb = (it + 1) & 1;
      const size_t so = ((size_t)(t0 + it + 1) << 12) + wq * 2048 + lane * 8;
#pragma unroll
      for (int s2 = 0; s2 < 4; s2++) {
        gl_lds16(kbase + so + s2 * 512, &sK[nb][wq * 2048 + s2 * 512]);
        gl_lds16(vbase + so + s2 * 512, &sV[nb][wq * 2048 + s2 * 512]);
      }
    }
    if (it < wq) continue;                    // tile fully below this wave's causal diag
    const u16* cK = sK[it & 1];
    const u16* cV = sV[it & 1];
    const int k0 = (t0 + it) * 64;
    const bool diag = (it == wq);

    // S^T then softmax per key-half kt2 (keeps accS live set at 32 VGPR)
#pragma unroll
    for (int kt2 = 0; kt2 < 2; kt2++) {
      bf8 aK[4];
#pragma unroll
      for (int kc = 0; kc < 4; kc++)
        aK[kc] = *(const bf8*)&cK[(kc >> 1) * 2048 + (kt2 * 32 + lm) * 32 + (kc & 1) * 16 + hi * 8];
      fx16 accS[2];
#pragma unroll
      for (int qt = 0; qt < 2; qt++) {
#pragma unroll
        for (int r = 0; r < 16; r++) accS[qt][r] = 0.f;
#pragma unroll
        for (int kc = 0; kc < 4; kc++)
          accS[qt] = __builtin_amdgcn_mfma_f32_32x32x16_bf16(aK[kc], bQ[qt][kc], accS[qt], 0, 0, 0);
      }
      // pen for this key-half: rows (r&3)+8*(r>>2)+4*hi
      fv4 pv[4];
#pragma unroll
      for (int g4 = 0; g4 < 4; g4++)
        pv[g4] = *(const fv4*)(penB + k0 + kt2 * 32 + g4 * 8 + hi * 4);
#pragma unroll
      for (int qt = 0; qt < 2; qt++) {
        float p[16];
#pragma unroll
        for (int r = 0; r < 16; r++) {
          float sv = fmaf(accS[qt][r], C2, -pv[r >> 2][r & 3]);
          if (diag) {
            const int key_in = kt2 * 32 + (r & 3) + 8 * (r >> 2) + 4 * hi;
            if (key_in <= qt * 32 + lm) sv -= BIG2F;
          }
          p[r] = exp2_hw(sv);
          l_part[qt] += p[r];
        }
        // P^T write: 4 x b64, rows of 4 consecutive keys
#pragma unroll
        for (int g4 = 0; g4 < 4; g4++) {
          u16x4 pk = { f2bf(p[g4 * 4]), f2bf(p[g4 * 4 + 1]), f2bf(p[g4 * 4 + 2]), f2bf(p[g4 * 4 + 3]) };
          *(u16x4*)&Pw[(qt * 32 + lm) * PS + kt2 * 32 + g4 * 8 + hi * 4] = pk;
        }
      }
    }

    // O^T += V^T P^T
    bf8 bP[2][4];
#pragma unroll
    for (int qt = 0; qt < 2; qt++)
#pragma unroll
      for (int kc = 0; kc < 4; kc++)
        bP[qt][kc] = *(const bf8*)&Pw[(qt * 32 + lm) * PS + kc * 16 + hi * 8];
#pragma unroll
    for (int dt2 = 0; dt2 < 2; dt2++) {
      bf8 aV[4];
#pragma unroll
      for (int kc = 0; kc < 4; kc++)
        aV[kc] = *(const bf8*)&cV[(kc >> 1) * 2048 + (dt2 * 32 + lm) * 32 + (kc & 1) * 16 + hi * 8];
#pragma unroll
      for (int qt = 0; qt < 2; qt++)
#pragma unroll
        for (int kc = 0; kc < 4; kc++)
          accO[dt2][qt] = __builtin_amdgcn_mfma_f32_32x32x16_bf16(aV[kc], bP[qt][kc], accO[dt2][qt], 0, 0, 0);
    }
  }

  // epilogue: per qt reduce l across hi halves, divide, q_mask, fv4 stores
#pragma unroll
  for (int qt = 0; qt < 2; qt++) {
    float l = l_part[qt] + __shfl_xor(l_part[qt], 32);
    const int q = q0 + wq * 64 + qt * 32 + lm;
    const float qm = qmask[b * SEQ + q];
    float* op = OUT + (size_t)(b * SEQ + q) * EMB + h * 64;
    if (l == 0.0f) {                          // dead row: masked-average fallback
#pragma unroll
      for (int dt2 = 0; dt2 < 2; dt2++)
#pragma unroll
        for (int g4 = 0; g4 < 4; g4++) {
          fv4 fbv = *(const fv4*)&fb[b * 1024 + h * 64 + dt2 * 32 + g4 * 8 + hi * 4];
          fbv *= qm;
          *(fv4*)(op + dt2 * 32 + g4 * 8 + hi * 4) = fbv;
        }
    } else {
      const float sc = qm / l;
#pragma unroll
      for (int dt2 = 0; dt2 < 2; dt2++)
#pragma unroll
        for (int g4 = 0; g4 < 4; g4++) {
          fv4 ov = { accO[dt2][qt][g4 * 4] * sc, accO[dt2][qt][g4 * 4 + 1] * sc,
                     accO[dt2][qt][g4 * 4 + 2] * sc, accO[dt2][qt][g4 * 4 + 3] * sc };
          *(fv4*)(op + dt2 * 32 + g4 * 8 + hi * 4) = ov;
        }
    }
  }
}

extern "C" void kernel_launch(void* const* d_in, const int* in_sizes, int n_in,
                              void* d_out, int out_size, void* d_ws, size_t ws_size,
                              hipStream_t stream)
{
  const float* q  = (const float*)d_in[0];
  const float* k  = (const float*)d_in[1];
  const float* v  = (const float*)d_in[2];
  const float* vm = (const float*)d_in[3];
  const float* qm = (const float*)d_in[4];
  const float* Wq = (const float*)d_in[5];
  const float* Wk = (const float*)d_in[6];
  const float* Wv = (const float*)d_in[7];
  float* out = (float*)d_out;

  const size_t NBIG = (size_t)B_ * SEQ * EMB;   // 4 Mi
  const size_t NW   = (size_t)EMB * EMB;        // 1 Mi

  u16* qb  = (u16*)d_ws;
  u16* kb  = qb  + NBIG;
  u16* vb  = kb  + NBIG;
  u16* Wqb = vb  + NBIG;
  u16* Wkb = Wqb + NW;
  u16* Wvb = Wkb + NW;
  u16* QH  = Wvb + NW;
  u16* KH  = QH  + NBIG;
  u16* VTB = KH  + NBIG;
  float* fb   = (float*)(VTB + NBIG);           // [2][1024] f32
  float* penG = fb + 2048;                      // [2][2048] f32

  CvtArgs ca;
  ca.src[0] = q;  ca.dst[0] = qb;          ca.n[0] = (int)NBIG;
  ca.src[1] = k;  ca.dst[1] = kb;          ca.n[1] = (int)NBIG;
  ca.src[2] = v;  ca.dst[2] = vb;          ca.n[2] = (int)NBIG;
  ca.src[3] = Wq; ca.dst[3] = Wqb;         ca.n[3] = (int)NW;
  ca.src[4] = Wk; ca.dst[4] = Wkb;         ca.n[4] = (int)NW;
  ca.src[5] = Wv; ca.dst[5] = Wvb;         ca.n[5] = (int)NW;
  ca.src[6] = vm; ca.dst[6] = (u16*)penG;  ca.n[6] = B_ * SEQ;

  cvt_bf16<<<dim3((unsigned)(NBIG / 8 / 256), 7, 1), 256, 0, stream>>>(ca);
  proj_gemm<<<dim3(32, 8, 3), 256, 0, stream>>>(qb, kb, vb, Wqb, Wkb, Wvb, QH, KH, VTB);
  sumv<<<dim3(64, 1, 1), 256, 0, stream>>>(VTB, vm, fb);
  attn<<<dim3(512, 1, 1), 128, 0, stream>>>(QH, KH, VTB, penG, qm, fb, out);
}